// Round 6
// baseline (237.028 us; speedup 1.0000x reference)
//
#include <hip/hip_runtime.h>

// NMS3D (4,4,32,256,256) fp32, strict 26-neighbor max.
// R5: 4-deep d-column per wave. Each wave loads rows of KD+2=6 planes and
// produces KD=4 d-outputs per h-step, cutting CU-delivered read bytes from
// 3.75x to (6/4)*(10/8) = 1.875x of the input (R0-R4 evidence: time tracks
// delivered bytes at ~7-8 TB/s aggregate; only byte reduction has moved it).
// Separable max: per-plane rolling h-window -> a3 (max of 3 h-rows), a2
// (h +-1); v8(d) = max(a3[d-1], a3[d+1], a2[d]); then horizontal max3 via
// lane shuffles. 3-slot modular renaming, HC=8 fully unrolled (no movs).
// One wave64 = one W row (64 lanes x float4); nontemporal stores.

typedef float v4f __attribute__((ext_vector_type(4)));

constexpr int W  = 256;
constexpr int H  = 256;
constexpr int D  = 32;
constexpr int SH = W;
constexpr int SD = W * H;
constexpr int KD = 4;                 // d outputs per wave
constexpr int HC = 8;                 // h rows per wave
constexpr int BC = 16;                // B*CH
constexpr int DG = D / KD;            // 8
constexpr int HG = H / HC;            // 32

__device__ __forceinline__ v4f vmax4(v4f a, v4f b) {
    return (v4f){fmaxf(a.x, b.x), fmaxf(a.y, b.y), fmaxf(a.z, b.z), fmaxf(a.w, b.w)};
}

__global__ __launch_bounds__(256) void nms3d_kernel(const float* __restrict__ x,
                                                    float* __restrict__ out) {
    const int wid  = (blockIdx.x << 2) | (threadIdx.x >> 6);
    const int lane = threadIdx.x & 63;
    const int hc   = wid & (HG - 1);              // block's 4 waves: consecutive hc
    const int dg   = (wid >> 5) & (DG - 1);
    const int bc   = wid >> 8;
    const int d0   = dg * KD;
    const int h0   = hc * HC;

    const float* vol  = x   + bc * (D * SD) + (lane << 2);
    float*       ovol = out + bc * (D * SD) + (lane << 2);

    // plane base pointers, clamped at volume edge (clamped planes feed only
    // zero-forced boundary outputs)
    const float* base[KD + 2];
    #pragma unroll
    for (int j = 0; j < KD + 2; ++j) {
        int p = d0 - 1 + j;
        p = p < 0 ? 0 : (p > D - 1 ? D - 1 : p);
        base[j] = vol + p * SD;
    }

    bool dvalid[KD];
    #pragma unroll
    for (int k = 0; k < KD; ++k) {
        const int dd = d0 + k;
        dvalid[k] = (dd > 0) && (dd < D - 1);
    }

    // rolling 3-row window per plane; slot (h mod 3) renaming via full unroll
    v4f r[KD + 2][3];
    {
        const int hm = (h0 - 1 < 0) ? 0 : h0 - 1;   // clamped row feeds only h=0 (zeroed)
        #pragma unroll
        for (int j = 0; j < KD + 2; ++j) r[j][0] = *(const v4f*)(base[j] + hm * SH);
        #pragma unroll
        for (int j = 0; j < KD + 2; ++j) r[j][1] = *(const v4f*)(base[j] + h0 * SH);
    }

    #pragma unroll
    for (int i = 0; i < HC; ++i) {
        const int h  = h0 + i;
        const int s0 = i % 3, s1 = (i + 1) % 3, s2 = (i + 2) % 3;

        const int hp = (h + 1 > H - 1) ? H - 1 : h + 1;   // clamp feeds only h=H-1 (zeroed)
        #pragma unroll
        for (int j = 0; j < KD + 2; ++j)
            r[j][s2] = *(const v4f*)(base[j] + hp * SH);

        v4f a2[KD + 2], a3[KD + 2];
        #pragma unroll
        for (int j = 0; j < KD + 2; ++j) {
            a2[j] = vmax4(r[j][s0], r[j][s2]);    // h-1, h+1
            a3[j] = vmax4(a2[j], r[j][s1]);       // all 3 h-rows
        }

        const bool hvalid = (h > 0) && (h < H - 1);   // wave-uniform

        #pragma unroll
        for (int k = 0; k < KD; ++k) {
            // 8 non-center rows of output d = d0+k
            v4f v8 = vmax4(vmax4(a3[k], a3[k + 2]), a2[k + 1]);
            const v4f c = r[k + 1][s1];
            float l8 = __shfl_up(v8.w, 1);    // lane0 garbage, masked
            float r8 = __shfl_down(v8.x, 1);  // lane63 garbage, masked
            float lc = __shfl_up(c.w, 1);
            float rc = __shfl_down(c.x, 1);

            float n0 = fmaxf(fmaxf(l8,   v8.x), v8.y);
            float n1 = fmaxf(fmaxf(v8.x, v8.y), v8.z);
            float n2 = fmaxf(fmaxf(v8.y, v8.z), v8.w);
            float n3 = fmaxf(fmaxf(v8.z, v8.w), r8);
            n0 = fmaxf(n0, fmaxf(lc,  c.y));
            n1 = fmaxf(n1, fmaxf(c.x, c.z));
            n2 = fmaxf(n2, fmaxf(c.y, c.w));
            n3 = fmaxf(n3, fmaxf(c.z, rc));

            const bool v = hvalid && dvalid[k];
            v4f o;
            o.x = (v && lane > 0  && c.x > n0) ? c.x : 0.f;
            o.y = (v && c.y > n1) ? c.y : 0.f;
            o.z = (v && c.z > n2) ? c.z : 0.f;
            o.w = (v && lane < 63 && c.w > n3) ? c.w : 0.f;
            __builtin_nontemporal_store(o, (v4f*)(ovol + (d0 + k) * SD + h * SH));
        }
    }
}

extern "C" void kernel_launch(void* const* d_in, const int* in_sizes, int n_in,
                              void* d_out, int out_size, void* d_ws, size_t ws_size,
                              hipStream_t stream) {
    const float* x = (const float*)d_in[0];
    float* out = (float*)d_out;
    // waves = BC * DG * HG = 16*8*32 = 4096; 4 waves/block -> 1024 blocks
    const int grid = (BC * DG * HG) / 4;
    nms3d_kernel<<<grid, 256, 0, stream>>>(x, out);
}

// Round 7
// 223.324 us; speedup vs baseline: 1.0614x; 1.0614x over previous
//
#include <hip/hip_runtime.h>

// NMS3D (4,4,32,256,256) fp32, strict 26-neighbor max.
// R6: LDS plane-staging via global_load_lds DMA.
// R1-R5 post-mortem: every register-resident pipeline was de-pipelined by the
// compiler (VGPR counts 36/68 for plans needing 120+ -> loads re-sunk to
// just-before-use with vmcnt(0) per use; all busy counters idle, waves stall
// thousands of cycles). Fix: loads become fire-and-forget LDS DMA that the
// compiler cannot reorder/sink; one vmcnt drain at the barrier.
//   Block (256 thr = 4 waves) owns (bc, 4 d's, 8 h-rows):
//     stage:   6 planes x 10 rows x 1 KiB = 60 KiB LDS, 15 DMA instrs/wave
//     compute: wave w -> d = d0+w, 8 output rows from LDS (ds_read_b128),
//              separable max + lane shuffles for w-edges, nt stores.
//   2 blocks/CU: one stages while the other computes.

typedef float v4f __attribute__((ext_vector_type(4)));

constexpr int W  = 256;
constexpr int H  = 256;
constexpr int D  = 32;
constexpr int SH = W;
constexpr int SD = W * H;
constexpr int KD = 4;                  // d outputs per block
constexpr int HC = 8;                  // h rows per block
constexpr int BC = 16;                 // B*CH
constexpr int DG = D / KD;             // 8
constexpr int HG = H / HC;             // 32
constexpr int NPL = KD + 2;            // 6 staged planes
constexpr int NR  = HC + 2;            // 10 staged rows per plane
constexpr int TROWS = NPL * NR;        // 60 rows of W floats

__device__ __forceinline__ v4f vmax4(v4f a, v4f b) {
    return (v4f){fmaxf(a.x, b.x), fmaxf(a.y, b.y), fmaxf(a.z, b.z), fmaxf(a.w, b.w)};
}

__global__ __launch_bounds__(256) void nms3d_kernel(const float* __restrict__ x,
                                                    float* __restrict__ out) {
    __shared__ float lds[TROWS * W];   // 60 KiB

    const int blk  = blockIdx.x;
    const int wv   = threadIdx.x >> 6;   // 0..3
    const int lane = threadIdx.x & 63;
    const int hc   = blk & (HG - 1);
    const int dg   = (blk >> 5) & (DG - 1);
    const int bc   = blk >> 8;
    const int d0   = dg * KD;
    const int h0   = hc * HC;

    const float* vol = x + bc * (D * SD);

    // ---- stage 60 rows; wave wv stages flat rows t = wv*15 .. wv*15+14 ----
    #pragma unroll
    for (int u = 0; u < TROWS / 4; ++u) {       // 15 DMA instrs per wave
        const int t = wv * (TROWS / 4) + u;
        const int j = t / NR;
        const int r = t - j * NR;
        int p = d0 - 1 + j;  p = p < 0 ? 0 : (p > D - 1 ? D - 1 : p);
        int hh = h0 - 1 + r; hh = hh < 0 ? 0 : (hh > H - 1 ? H - 1 : hh);
        const float* gp = vol + p * SD + hh * SH + (lane << 2);
        // lane i's 16B land at ldsbase + 16*i -> exactly row-major row layout
        __builtin_amdgcn_global_load_lds(
            (const __attribute__((address_space(1))) unsigned int*)gp,
            (__attribute__((address_space(3))) unsigned int*)&lds[(j * NR + r) * W],
            16, 0, 0);
    }
    __syncthreads();   // drains vmcnt (DMA) then barrier

    // ---- compute: wave wv handles output plane d = d0 + wv ----
    const int d = d0 + wv;
    const bool dv = (d > 0) && (d < D - 1);
    float* ovol = out + bc * (D * SD) + d * SD + (lane << 2);

    const float* Lm = lds + (wv * NR) * W + (lane << 2);        // plane d-1
    const float* L0 = lds + ((wv + 1) * NR) * W + (lane << 2);  // plane d
    const float* Lp = lds + ((wv + 2) * NR) * W + (lane << 2);  // plane d+1

    // rolling 3-row window per plane, slot = (row mod 3), fully unrolled
    v4f rm[3], r0[3], rp[3];
    rm[0] = *(const v4f*)(Lm + 0 * W); r0[0] = *(const v4f*)(L0 + 0 * W); rp[0] = *(const v4f*)(Lp + 0 * W);
    rm[1] = *(const v4f*)(Lm + 1 * W); r0[1] = *(const v4f*)(L0 + 1 * W); rp[1] = *(const v4f*)(Lp + 1 * W);

    #pragma unroll
    for (int i = 0; i < HC; ++i) {
        const int s0 = i % 3, s1 = (i + 1) % 3, s2 = (i + 2) % 3;
        rm[s2] = *(const v4f*)(Lm + (i + 2) * W);
        r0[s2] = *(const v4f*)(L0 + (i + 2) * W);
        rp[s2] = *(const v4f*)(Lp + (i + 2) * W);

        // separable: per-plane maxes over the 3 h-rows
        const v4f a3m = vmax4(vmax4(rm[s0], rm[s1]), rm[s2]);   // plane d-1, all rows
        const v4f a3p = vmax4(vmax4(rp[s0], rp[s1]), rp[s2]);   // plane d+1, all rows
        const v4f a20 = vmax4(r0[s0], r0[s2]);                  // plane d, h +- 1
        const v4f v8  = vmax4(vmax4(a3m, a3p), a20);            // 8 non-center rows
        const v4f c   = r0[s1];

        const float l8 = __shfl_up(v8.w, 1);     // lane0 garbage, masked
        const float r8 = __shfl_down(v8.x, 1);   // lane63 garbage, masked
        const float lc = __shfl_up(c.w, 1);
        const float rc = __shfl_down(c.x, 1);

        float n0 = fmaxf(fmaxf(l8,   v8.x), v8.y);
        float n1 = fmaxf(fmaxf(v8.x, v8.y), v8.z);
        float n2 = fmaxf(fmaxf(v8.y, v8.z), v8.w);
        float n3 = fmaxf(fmaxf(v8.z, v8.w), r8);
        n0 = fmaxf(n0, fmaxf(lc,  c.y));
        n1 = fmaxf(n1, fmaxf(c.x, c.z));
        n2 = fmaxf(n2, fmaxf(c.y, c.w));
        n3 = fmaxf(n3, fmaxf(c.z, rc));

        const int h = h0 + i;
        const bool hv = (h > 0) && (h < H - 1);   // wave-uniform
        const bool v  = hv && dv;
        v4f o;
        o.x = (v && lane > 0  && c.x > n0) ? c.x : 0.f;
        o.y = (v && c.y > n1) ? c.y : 0.f;
        o.z = (v && c.z > n2) ? c.z : 0.f;
        o.w = (v && lane < 63 && c.w > n3) ? c.w : 0.f;
        __builtin_nontemporal_store(o, (v4f*)(ovol + h * SH));
    }
}

extern "C" void kernel_launch(void* const* d_in, const int* in_sizes, int n_in,
                              void* d_out, int out_size, void* d_ws, size_t ws_size,
                              hipStream_t stream) {
    const float* x = (const float*)d_in[0];
    float* out = (float*)d_out;
    // blocks = BC * DG * HG = 16*8*32 = 4096, 256 threads each
    const int grid = BC * DG * HG;
    nms3d_kernel<<<grid, 256, 0, stream>>>(x, out);
}